// Round 1
// baseline (346.081 us; speedup 1.0000x reference)
//
#include <hip/hip_runtime.h>
#include <stdint.h>

// Problem constants (fixed by the reference).
#define B_TOTAL 16384
#define F 512
#define L 256
#define TB 32      // batch rows per block
#define KC 64      // K-chunk per LDS stage
#define LDP 72     // padded LDS row stride in f16 elems (144 B = 36 banks -> 2-way aliasing, free)

typedef _Float16 half8 __attribute__((ext_vector_type(8)));
typedef float floatx4 __attribute__((ext_vector_type(4)));

// Pre-retiled f16 weights: [which][kstep][l][kc]  (kstep = f/64, kc = f%64)
// Static device buffer: avoids d_ws (unknown size) and is rewritten every launch
// (same work each call -> graph-capture safe).
__device__ __align__(16) _Float16 g_wt[2][8][L][KC];

__global__ void wconv_kernel(const float* __restrict__ uW,
                             const float* __restrict__ iW) {
    int tid = blockIdx.x * blockDim.x + threadIdx.x;   // 0 .. 262143
    int which = tid >> 17;                             // 131072 elems per matrix
    int r = tid & 131071;
    int l = r >> 9;        // 0..255
    int f = r & 511;       // 0..511
    float v = which ? iW[r] : uW[r];
    g_wt[which][f >> 6][l][f & 63] = (_Float16)v;      // RNE hw convert
}

__launch_bounds__(256, 3)
__global__ void fused_kernel(const int* __restrict__ x,
                             const float* __restrict__ ulook,
                             const float* __restrict__ ilook,
                             const float* __restrict__ ub,
                             const float* __restrict__ ib,
                             float* __restrict__ out) {
    __shared__ _Float16 sA[TB][LDP];   // gathered feature tile (f16)
    __shared__ _Float16 sB[L][LDP];    // weight tile (f16)
    __shared__ float    sRed[TB];      // per-row dot accumulator
    __shared__ int      sIdx[2][TB];   // [user/item][row]

    const int t = threadIdx.x;
    const int bbase = blockIdx.x * TB;

    if (t < 2 * TB) {
        int r = t >> 1, c = t & 1;
        sIdx[c][r] = x[(bbase + r) * 2 + c];
    }
    if (t < TB) sRed[t] = 0.0f;
    __syncthreads();

    const int wave = t >> 6;
    const int lane = t & 63;
    const int l15  = lane & 15;
    const int quad = lane >> 4;
    const int nbase = wave * 64;      // this wave's 64-wide N chunk

    // user-pass latents kept in registers: pass-1 lane re-reads exactly the
    // (m,n) cells it computed in pass 0 (same lane/wave formulas).
    floatx4 ulat[2][4];
    floatx4 acc[2][4];

    // A-stage addressing (uniform per thread across steps)
    const int arow = t >> 3;            // 0..31
    const int aoff = (t & 7) * 8;       // 0..56

    #pragma unroll 1
    for (int pass = 0; pass < 2; ++pass) {
        const float* __restrict__ look = pass ? ilook : ulook;
        const float* __restrict__ bias = pass ? ib : ub;

        #pragma unroll
        for (int mt = 0; mt < 2; ++mt)
            #pragma unroll
            for (int nt = 0; nt < 4; ++nt) {
                floatx4 z = {0.f, 0.f, 0.f, 0.f};
                acc[mt][nt] = z;
            }

        const int rowidx = sIdx[pass][arow];
        const float* asrc_base = look + (size_t)rowidx * F + aoff;

        #pragma unroll 1
        for (int ks = 0; ks < 8; ++ks) {
            __syncthreads();   // protect LDS tiles from previous step's readers

            // ---- stage A: gather 32 rows x 64 cols fp32 -> f16 LDS ----
            {
                const float* src = asrc_base + ks * KC;
                float4 v0 = *(const float4*)(src);
                float4 v1 = *(const float4*)(src + 4);
                _Float16 h[8];
                h[0] = (_Float16)v0.x; h[1] = (_Float16)v0.y;
                h[2] = (_Float16)v0.z; h[3] = (_Float16)v0.w;
                h[4] = (_Float16)v1.x; h[5] = (_Float16)v1.y;
                h[6] = (_Float16)v1.z; h[7] = (_Float16)v1.w;
                *(half8*)(&sA[arow][aoff]) = *(half8*)h;
            }
            // ---- stage B: contiguous 32 KB copy from pre-tiled f16 W ----
            {
                const _Float16* src = &g_wt[pass][ks][0][0];  // 16384 f16 contiguous
                #pragma unroll
                for (int i = 0; i < 8; ++i) {
                    int c = t + 256 * i;          // 0..2047 chunks of 8 f16
                    int rowb = c >> 3;
                    int offb = (c & 7) * 8;
                    uint4 v = *(const uint4*)(src + c * 8);
                    *(uint4*)(&sB[rowb][offb]) = v;
                }
            }
            __syncthreads();

            // ---- MFMA: 2 k-tiles of 32 ----
            #pragma unroll
            for (int kt = 0; kt < 2; ++kt) {
                half8 af[2], bfr[4];
                #pragma unroll
                for (int mt = 0; mt < 2; ++mt)
                    af[mt] = *(const half8*)(&sA[mt * 16 + l15][kt * 32 + quad * 8]);
                #pragma unroll
                for (int nt = 0; nt < 4; ++nt)
                    bfr[nt] = *(const half8*)(&sB[nbase + nt * 16 + l15][kt * 32 + quad * 8]);
                #pragma unroll
                for (int mt = 0; mt < 2; ++mt)
                    #pragma unroll
                    for (int nt = 0; nt < 4; ++nt)
                        acc[mt][nt] = __builtin_amdgcn_mfma_f32_16x16x32_f16(
                            af[mt], bfr[nt], acc[mt][nt], 0, 0, 0);
            }
        }

        // ---- epilogue ----
        if (pass == 0) {
            #pragma unroll
            for (int mt = 0; mt < 2; ++mt)
                #pragma unroll
                for (int nt = 0; nt < 4; ++nt) {
                    int n = nbase + nt * 16 + l15;
                    float bv = bias[n];
                    #pragma unroll
                    for (int r = 0; r < 4; ++r) {
                        float v = acc[mt][nt][r] + bv;
                        ulat[mt][nt][r] = v > 0.f ? v : 0.f;
                    }
                }
        } else {
            #pragma unroll
            for (int mt = 0; mt < 2; ++mt) {
                float partial[4] = {0.f, 0.f, 0.f, 0.f};
                #pragma unroll
                for (int nt = 0; nt < 4; ++nt) {
                    int n = nbase + nt * 16 + l15;
                    float bv = bias[n];
                    #pragma unroll
                    for (int r = 0; r < 4; ++r) {
                        float v = acc[mt][nt][r] + bv;
                        v = v > 0.f ? v : 0.f;
                        partial[r] += v * ulat[mt][nt][r];
                    }
                }
                #pragma unroll
                for (int r = 0; r < 4; ++r) {
                    float v = partial[r];
                    v += __shfl_xor(v, 1);
                    v += __shfl_xor(v, 2);
                    v += __shfl_xor(v, 4);
                    v += __shfl_xor(v, 8);
                    if (l15 == 0)
                        atomicAdd(&sRed[mt * 16 + quad * 4 + r], v);
                }
            }
        }
    }

    __syncthreads();
    if (t < TB) out[bbase + t] = sRed[t];
}

extern "C" void kernel_launch(void* const* d_in, const int* in_sizes, int n_in,
                              void* d_out, int out_size, void* d_ws, size_t ws_size,
                              hipStream_t stream) {
    const int*   x     = (const int*)d_in[0];
    const float* ulook = (const float*)d_in[1];
    const float* ilook = (const float*)d_in[2];
    const float* uW    = (const float*)d_in[3];
    const float* ub    = (const float*)d_in[4];
    const float* iW    = (const float*)d_in[5];
    const float* ib    = (const float*)d_in[6];
    float* out = (float*)d_out;

    wconv_kernel<<<1024, 256, 0, stream>>>(uW, iW);
    fused_kernel<<<B_TOTAL / TB, 256, 0, stream>>>(x, ulook, ilook, ub, ib, out);
}